// Round 1
// 203.425 us; speedup vs baseline: 1.0094x; 1.0094x over previous
//
#include <hip/hip_runtime.h>

#define TC 128
#define KD 64
#define WLOG_MIN (-5.2983174f)   // ln(0.005)

typedef __attribute__((ext_vector_type(8))) short short8;
typedef __attribute__((ext_vector_type(4))) short short4_t;
typedef __attribute__((ext_vector_type(4))) float f32x4;

__device__ __forceinline__ unsigned short f2bf(float x) {
  union { float f; unsigned int u; } c; c.f = x;
  unsigned int u = c.u + 0x7fffu + ((c.u >> 16) & 1u);   // RNE
  return (unsigned short)(u >> 16);
}
__device__ __forceinline__ float bf2f(unsigned short x) {
  union { unsigned int u; float f; } c; c.u = ((unsigned int)x) << 16; return c.f;
}

// rd_s/ki_s swizzle: element (t,kd) stored at t*64 + (slot<<3 | kd&7),
// slot = (kd>>3) ^ (t&7) ^ ((t>>3)&7).  b128 granule-q reads use
// slot = q ^ (t&7) ^ ((t>>3)&7).  vT/sT swizzle: slot = g ^ (row&7).

// ---------------------------------------------------------------------------
// K1: per-(b,h,chunk). 54,272B LDS -> 3 blocks/CU. Two barriers. (unchanged)
// ---------------------------------------------------------------------------
__global__ __launch_bounds__(256, 3)
void rwkv_intra_mfma(const float* __restrict__ rr, const float* __restrict__ kk_,
                     const float* __restrict__ vv, const float* __restrict__ ww,
                     const float* __restrict__ uu, float* __restrict__ out,
                     unsigned short* __restrict__ wkv_u16, float* __restrict__ wse_ws,
                     unsigned short* __restrict__ rw_u16, unsigned short* __restrict__ diag_u16,
                     int H, int N) {
  __shared__ alignas(16) unsigned short rd_s[TC * KD];
  __shared__ alignas(16) unsigned short ki_s[TC * KD];
  __shared__ alignas(16) unsigned short vT_s[KD * TC];
  __shared__ alignas(16) unsigned char su_raw[5120];   // union: segtot f32[4][64] | Ast u16[4][640]
  float* segtot = (float*)su_raw;
  unsigned short* Ast = (unsigned short*)su_raw;

  const int bid = blockIdx.x;
  const int n = bid % N, bh = bid / N, h = bh % H;
  const size_t base = ((size_t)bh * N + n) * (TC * KD);
  const float *rg = rr + base, *kg = kk_ + base, *vg = vv + base, *wg = ww + base;
  unsigned short* diagg = diag_u16 + (size_t)bid * TC;

  const int tid = threadIdx.x;
  const int lk = tid & 63;    // k-column during staging
  const int wv = tid >> 6;    // wave id = t-segment

  // ---- pass 1: w (regs) + segment totals ----
  float wl[32];
  {
    float c = 0.f;
    #pragma unroll
    for (int tt = 0; tt < 32; ++tt) {
      wl[tt] = fmaxf(wg[(wv * 32 + tt) * KD + lk], WLOG_MIN);
      c += wl[tt];
    }
    segtot[wv * 64 + lk] = c;
  }
  __syncthreads();
  const float s0 = segtot[0 * 64 + lk], s1 = segtot[1 * 64 + lk];
  const float s2 = segtot[2 * 64 + lk], s3 = segtot[3 * 64 + lk];
  const float myoff = s0 + s1;   // cum at t = Tc/2
  const float segofs = (wv == 0) ? 0.f : (wv == 1) ? s0 : (wv == 2) ? (s0 + s1) : (s0 + s1 + s2);
  const float wsum = s0 + s1 + s2 + s3;
  const float wsoff_own = __expf(wsum - myoff);   // kept in reg (segtot gets clobbered by Ast)
  if (wv == 0) wse_ws[((size_t)bh * N + n) * KD + lk] = __expf(wsum);
  const float eoff = __expf(myoff);

  // ---- pass 2: staging ----
  {
    float c = segofs;
    const float uk = uu[h * KD + lk];
    unsigned short* rwg = rw_u16 + base;
    short8 vb8;
    float darr[8];
    #pragma unroll
    for (int tt = 0; tt < 32; ++tt) {
      const int t = wv * 32 + tt;
      float rv = rg[t * KD + lk], kv = kg[t * KD + lk], vvv = vg[t * KD + lk];
      const int slot = (lk >> 3) ^ (t & 7) ^ ((t >> 3) & 7);
      const int nat = t * KD + (slot << 3) + (lk & 7);
      float e1 = __expf(c - myoff);
      rd_s[nat] = f2bf(rv * e1);
      rwg[t * KD + lk] = f2bf(rv * e1 * eoff);  // r * exp(cum) for scan_inter
      ki_s[nat] = f2bf(kv * __expf(myoff - c - wl[tt]));
      vb8[tt & 7] = (short)f2bf(vvv);
      darr[tt & 7] = rv * uk * kv;
      c += wl[tt];
      if ((tt & 7) == 7) {
        const int g = t >> 3;
        *(short8*)&vT_s[lk * TC + ((g ^ (lk & 7)) << 3)] = vb8;
        // batched butterfly: 8 independent reductions
        #pragma unroll
        for (int o = 32; o > 0; o >>= 1)
          #pragma unroll
          for (int q = 0; q < 8; ++q) darr[q] += __shfl_xor(darr[q], o, 64);
        if (lk == 0) {
          short8 dpk;
          #pragma unroll
          for (int q = 0; q < 8; ++q) dpk[q] = (short)f2bf(darr[q]);
          *(short8*)&diagg[g * 8] = dpk;
        }
      }
    }
  }
  __syncthreads();

  const int lane = tid & 63, quad = lane >> 4, l16 = lane & 15;

  // ---- wkv = (ki * w_inter)^T @ v -> bf16 ws (A-frags via scalar LDS reads) ----
  {
    f32x4 acc[4] = {{0,0,0,0},{0,0,0,0},{0,0,0,0},{0,0,0,0}};
    const int kdg = wv * 2 + (l16 >> 3), kd7 = l16 & 7;
    #pragma unroll
    for (int ks = 0; ks < 4; ++ks) {
      short8 a;
      #pragma unroll
      for (int j = 0; j < 8; ++j) {
        const int t = ks * 32 + quad * 8 + j;
        a[j] = (short)ki_s[t * KD + (((kdg ^ (t & 7) ^ ((t >> 3) & 7)) << 3) + kd7)];
      }
      #pragma unroll
      for (int nn = 0; nn < 4; ++nn) {
        const int vd = nn * 16 + l16;
        short8 b = *(const short8*)&vT_s[vd * TC + (((ks * 4 + quad) ^ (vd & 7)) << 3)];
        acc[nn] = __builtin_amdgcn_mfma_f32_16x16x32_bf16(a, b, acc[nn], 0, 0, 0);
      }
    }
    float wso[4];
    #pragma unroll
    for (int reg = 0; reg < 4; ++reg) wso[reg] = __shfl(wsoff_own, wv * 16 + quad * 4 + reg, 64);
    unsigned short* wkvg = wkv_u16 + ((size_t)bh * N + n) * (KD * KD);
    #pragma unroll
    for (int nn = 0; nn < 4; ++nn)
      #pragma unroll
      for (int reg = 0; reg < 4; ++reg)
        wkvg[(wv * 16 + quad * 4 + reg) * KD + nn * 16 + l16] = f2bf(acc[nn][reg] * wso[reg]);
  }

  // ---- fused A^T tiles + out = A@v (per-wave, no block sync) ----
  #pragma unroll
  for (int half = 0; half < 2; ++half) {
    const int ib = half ? (7 - wv) : wv;
    const int i0 = ib * 16;
    const int irow = i0 + l16;
    const int rsw = (irow & 7) ^ ((irow >> 3) & 7);
    short8 b0 = *(const short8*)&rd_s[irow * KD + ((quad ^ rsw) << 3)];
    short8 b1 = *(const short8*)&rd_s[irow * KD + (((4 + quad) ^ rsw) << 3)];
    const float diag_i = bf2f(diagg[irow]);
    f32x4 oacc[4] = {{0,0,0,0},{0,0,0,0},{0,0,0,0},{0,0,0,0}};
    const int npairs = (ib + 2) >> 1;
    unsigned short* astw = Ast + wv * 640;
    for (int jp = 0; jp < npairs; ++jp) {
      #pragma unroll
      for (int jj = 0; jj < 2; ++jj) {
        const int j = jp * 2 + jj;
        short4_t pk;
        if (j <= ib) {
          const int jrow = j * 16 + l16;
          const int jsw = (jrow & 7) ^ ((jrow >> 3) & 7);
          short8 a0 = *(const short8*)&ki_s[jrow * KD + ((quad ^ jsw) << 3)];
          short8 a1 = *(const short8*)&ki_s[jrow * KD + (((4 + quad) ^ jsw) << 3)];
          f32x4 at = {0, 0, 0, 0};
          at = __builtin_amdgcn_mfma_f32_16x16x32_bf16(a0, b0, at, 0, 0, 0);
          at = __builtin_amdgcn_mfma_f32_16x16x32_bf16(a1, b1, at, 0, 0, 0);
          #pragma unroll
          for (int reg = 0; reg < 4; ++reg) {
            const int je = j * 16 + quad * 4 + reg;
            float val = at[reg];
            if (j == ib) val = (je < irow) ? val : ((je == irow) ? diag_i : 0.f);
            pk[reg] = (short)f2bf(val);
          }
        } else {
          pk = (short4_t)0;  // guard half for even ib
        }
        *(short4_t*)&astw[l16 * 40 + jj * 16 + quad * 4] = pk;
      }
      short8 af = *(const short8*)&astw[l16 * 40 + quad * 8];
      #pragma unroll
      for (int nn = 0; nn < 4; ++nn) {
        const int vd = nn * 16 + l16;
        short8 bv = *(const short8*)&vT_s[vd * TC + (((jp * 4 + quad) ^ (vd & 7)) << 3)];
        oacc[nn] = __builtin_amdgcn_mfma_f32_16x16x32_bf16(af, bv, oacc[nn], 0, 0, 0);
      }
    }
    float* og = out + base;
    #pragma unroll
    for (int nn = 0; nn < 4; ++nn)
      #pragma unroll
      for (int reg = 0; reg < 4; ++reg)
        og[(i0 + quad * 4 + reg) * KD + nn * 16 + l16] = oacc[nn][reg];
  }
}

// ---------------------------------------------------------------------------
// K2a (state scan only): block = (bh, vd-16-slab), 256 blocks. Pure f32
// register scan over the 16 chunks; writes each PRE-update state S_n as
// bf16 IN-PLACE over the wkv slot it just consumed (no workspace growth).
// Per-iter __syncthreads (implicit vmcnt(0) drain) separates all threads'
// prefetch-reads of slot n (issued at iter n-1) from the writes at iter n.
// No LDS, no MFMA; traffic ~17 MB total -> latency-bound but tiny.
// ---------------------------------------------------------------------------
__global__ __launch_bounds__(256)
void rwkv_scan_states(const float* __restrict__ wse_ws,
                      const float* __restrict__ st_in,
                      unsigned short* __restrict__ wkv_u16,   // in: wkv; out: states S_n (in-place)
                      float* __restrict__ final_out, int N) {
  const int bh = blockIdx.x >> 2, vq = blockIdx.x & 3;
  const int tid = threadIdx.x;
  const int vd_l = tid & 15, kd0 = (tid >> 4) * 4;
  const size_t sbase = (size_t)bh * (KD * KD);

  float stt[4];
  #pragma unroll
  for (int j = 0; j < 4; ++j)
    stt[j] = st_in[sbase + (kd0 + j) * KD + vq * 16 + vd_l];

  float nwk[4], nwe[4];
  #pragma unroll
  for (int j = 0; j < 4; ++j) {
    nwk[j] = bf2f(wkv_u16[(size_t)bh * N * (KD * KD) + (kd0 + j) * KD + vq * 16 + vd_l]);
    nwe[j] = wse_ws[(size_t)bh * N * KD + kd0 + j];
  }

  for (int n = 0; n < N; ++n) {
    float cwk[4], cwe[4];
    #pragma unroll
    for (int j = 0; j < 4; ++j) { cwk[j] = nwk[j]; cwe[j] = nwe[j]; }
    if (n + 1 < N) {
      const size_t b2 = (size_t)bh * N + n + 1;
      #pragma unroll
      for (int j = 0; j < 4; ++j) {
        nwk[j] = bf2f(wkv_u16[b2 * (KD * KD) + (kd0 + j) * KD + vq * 16 + vd_l]);
        nwe[j] = wse_ws[b2 * KD + kd0 + j];
      }
    }
    __syncthreads();   // all reads of slot n complete before we overwrite it
    unsigned short* sg = wkv_u16 + ((size_t)bh * N + n) * (KD * KD);
    #pragma unroll
    for (int j = 0; j < 4; ++j)
      sg[(kd0 + j) * KD + vq * 16 + vd_l] = f2bf(stt[j]);
    #pragma unroll
    for (int j = 0; j < 4; ++j) stt[j] = stt[j] * cwe[j] + cwk[j];
  }
  #pragma unroll
  for (int j = 0; j < 4; ++j)
    final_out[sbase + (kd0 + j) * KD + vq * 16 + vd_l] = stt[j];
}

// ---------------------------------------------------------------------------
// K2b (inter apply, fully parallel): block = (bh, n), BH*N = 1024 blocks,
// 8 KB LDS -> all blocks co-resident (4 blocks/CU). Stage S_n^T (transpose
// + sT swizzle) into LDS, then out += rw @ S_n with the same MFMA pattern
// as the old fused K2 (rw A-frags straight from global, coalesced).
// ---------------------------------------------------------------------------
__global__ __launch_bounds__(256)
void rwkv_apply_inter(const unsigned short* __restrict__ st_u16,  // states from K2a (wkv buffer)
                      const unsigned short* __restrict__ rw_u16,
                      float* __restrict__ out, int N) {
  __shared__ alignas(16) unsigned short sT[KD * KD];  // [vd][kd] swizzled, 8 KB
  const int bid = blockIdx.x;
  const int n = bid % N, bh = bid / N;
  const int tid = threadIdx.x;

  // stage S_n^T into LDS: thread reads 16 contiguous vd of row kd, writes
  // transposed with slot = (kd>>3) ^ (vd&7), low bits kd&7.
  {
    const unsigned short* sg = st_u16 + ((size_t)bh * N + n) * (KD * KD);
    const int kd = tid >> 2, v0 = (tid & 3) * 16;
    short8 x0 = *(const short8*)&sg[kd * KD + v0];
    short8 x1 = *(const short8*)&sg[kd * KD + v0 + 8];
    const int g = kd >> 3, k7 = kd & 7;
    #pragma unroll
    for (int i = 0; i < 8; ++i) {
      int vd = v0 + i;
      sT[vd * KD + (((g ^ (vd & 7)) << 3) | k7)] = (unsigned short)x0[i];
      vd = v0 + 8 + i;
      sT[vd * KD + (((g ^ (vd & 7)) << 3) | k7)] = (unsigned short)x1[i];
    }
  }
  __syncthreads();

  const int lane = tid & 63, wv = tid >> 6, quad = lane >> 4, l16 = lane & 15;
  const unsigned short* rwg = rw_u16 + ((size_t)bh * N + n) * (TC * KD);
  float* og = out + ((size_t)bh * N + n) * (TC * KD);
  #pragma unroll
  for (int half = 0; half < 2; ++half) {
    const int mt = wv + half * 4;
    const int trow = mt * 16 + l16;
    short8 a0 = *(const short8*)&rwg[trow * KD + quad * 8];
    short8 a1 = *(const short8*)&rwg[trow * KD + 32 + quad * 8];
    #pragma unroll
    for (int nn = 0; nn < 4; ++nn) {
      const int vd = nn * 16 + l16;
      short8 b0 = *(const short8*)&sT[vd * KD + ((quad ^ (vd & 7)) << 3)];
      short8 b1 = *(const short8*)&sT[vd * KD + (((4 + quad) ^ (vd & 7)) << 3)];
      f32x4 acc = {0, 0, 0, 0};
      acc = __builtin_amdgcn_mfma_f32_16x16x32_bf16(a0, b0, acc, 0, 0, 0);
      acc = __builtin_amdgcn_mfma_f32_16x16x32_bf16(a1, b1, acc, 0, 0, 0);
      #pragma unroll
      for (int reg = 0; reg < 4; ++reg) {
        const size_t oi = (size_t)(mt * 16 + quad * 4 + reg) * KD + nn * 16 + l16;
        og[oi] += acc[reg];
      }
    }
  }
}

// ---------------------------------------------------------------------------
// Workspace (~24.75 MB): [wkv u16: BH*N*K*K (reused in-place for states)]
//                        [wse f32: BH*N*K][rw u16: BH*T*K][diag u16: BH*N*TC]
// ---------------------------------------------------------------------------
extern "C" void kernel_launch(void* const* d_in, const int* in_sizes, int n_in,
                              void* d_out, int out_size, void* d_ws, size_t ws_size,
                              hipStream_t stream) {
  const float* r = (const float*)d_in[0];
  const float* k = (const float*)d_in[1];
  const float* v = (const float*)d_in[2];
  const float* w = (const float*)d_in[3];
  const float* u = (const float*)d_in[4];
  const float* st0 = (const float*)d_in[5];
  float* out = (float*)d_out;

  const int BH = in_sizes[5] / (KD * KD);  // 64
  const int H = in_sizes[4] / KD;          // 16
  const int T = in_sizes[0] / (BH * KD);   // 2048
  const int N = T / TC;                    // 16

  unsigned short* wkv_u16 = (unsigned short*)d_ws;
  float* wse_ws = (float*)(wkv_u16 + (size_t)BH * N * KD * KD);
  unsigned short* rw_u16 = (unsigned short*)(wse_ws + (size_t)BH * N * KD);
  unsigned short* diag_u16 = rw_u16 + (size_t)BH * T * KD;
  float* final_out = out + (size_t)in_sizes[0];

  rwkv_intra_mfma<<<BH * N, 256, 0, stream>>>(r, k, v, w, u, out, wkv_u16, wse_ws,
                                              rw_u16, diag_u16, H, N);
  rwkv_scan_states<<<BH * 4, 256, 0, stream>>>(wse_ws, st0, wkv_u16, final_out, N);
  rwkv_apply_inter<<<BH * N, 256, 0, stream>>>(wkv_u16, rw_u16, out, N);
}

// Round 2
// 198.485 us; speedup vs baseline: 1.0345x; 1.0249x over previous
//
#include <hip/hip_runtime.h>

#define TC 128
#define KD 64
#define WLOG_MIN (-5.2983174f)   // ln(0.005)

typedef __attribute__((ext_vector_type(8))) short short8;
typedef __attribute__((ext_vector_type(4))) short short4_t;
typedef __attribute__((ext_vector_type(4))) float f32x4;

__device__ __forceinline__ unsigned short f2bf(float x) {
  union { float f; unsigned int u; } c; c.f = x;
  unsigned int u = c.u + 0x7fffu + ((c.u >> 16) & 1u);   // RNE
  return (unsigned short)(u >> 16);
}
__device__ __forceinline__ float bf2f(unsigned short x) {
  union { unsigned int u; float f; } c; c.u = ((unsigned int)x) << 16; return c.f;
}

// rd_s/ki_s swizzle: element (t,kd) stored at t*64 + (slot<<3 | kd&7),
// slot = (kd>>3) ^ (t&7) ^ ((t>>3)&7).  b128 granule-q reads use
// slot = q ^ (t&7) ^ ((t>>3)&7).  vT/sT swizzle: slot = g ^ (row&7).

// ---------------------------------------------------------------------------
// K1: per-(b,h,chunk). 54,272B LDS -> 3 blocks/CU. Two barriers. (unchanged)
// ---------------------------------------------------------------------------
__global__ __launch_bounds__(256, 3)
void rwkv_intra_mfma(const float* __restrict__ rr, const float* __restrict__ kk_,
                     const float* __restrict__ vv, const float* __restrict__ ww,
                     const float* __restrict__ uu, float* __restrict__ out,
                     unsigned short* __restrict__ wkv_u16, float* __restrict__ wse_ws,
                     unsigned short* __restrict__ rw_u16, unsigned short* __restrict__ diag_u16,
                     int H, int N) {
  __shared__ alignas(16) unsigned short rd_s[TC * KD];
  __shared__ alignas(16) unsigned short ki_s[TC * KD];
  __shared__ alignas(16) unsigned short vT_s[KD * TC];
  __shared__ alignas(16) unsigned char su_raw[5120];   // union: segtot f32[4][64] | Ast u16[4][640]
  float* segtot = (float*)su_raw;
  unsigned short* Ast = (unsigned short*)su_raw;

  const int bid = blockIdx.x;
  const int n = bid % N, bh = bid / N, h = bh % H;
  const size_t base = ((size_t)bh * N + n) * (TC * KD);
  const float *rg = rr + base, *kg = kk_ + base, *vg = vv + base, *wg = ww + base;
  unsigned short* diagg = diag_u16 + (size_t)bid * TC;

  const int tid = threadIdx.x;
  const int lk = tid & 63;    // k-column during staging
  const int wv = tid >> 6;    // wave id = t-segment

  // ---- pass 1: w (regs) + segment totals ----
  float wl[32];
  {
    float c = 0.f;
    #pragma unroll
    for (int tt = 0; tt < 32; ++tt) {
      wl[tt] = fmaxf(wg[(wv * 32 + tt) * KD + lk], WLOG_MIN);
      c += wl[tt];
    }
    segtot[wv * 64 + lk] = c;
  }
  __syncthreads();
  const float s0 = segtot[0 * 64 + lk], s1 = segtot[1 * 64 + lk];
  const float s2 = segtot[2 * 64 + lk], s3 = segtot[3 * 64 + lk];
  const float myoff = s0 + s1;   // cum at t = Tc/2
  const float segofs = (wv == 0) ? 0.f : (wv == 1) ? s0 : (wv == 2) ? (s0 + s1) : (s0 + s1 + s2);
  const float wsum = s0 + s1 + s2 + s3;
  const float wsoff_own = __expf(wsum - myoff);   // kept in reg (segtot gets clobbered by Ast)
  if (wv == 0) wse_ws[((size_t)bh * N + n) * KD + lk] = __expf(wsum);
  const float eoff = __expf(myoff);

  // ---- pass 2: staging ----
  {
    float c = segofs;
    const float uk = uu[h * KD + lk];
    unsigned short* rwg = rw_u16 + base;
    short8 vb8;
    float darr[8];
    #pragma unroll
    for (int tt = 0; tt < 32; ++tt) {
      const int t = wv * 32 + tt;
      float rv = rg[t * KD + lk], kv = kg[t * KD + lk], vvv = vg[t * KD + lk];
      const int slot = (lk >> 3) ^ (t & 7) ^ ((t >> 3) & 7);
      const int nat = t * KD + (slot << 3) + (lk & 7);
      float e1 = __expf(c - myoff);
      rd_s[nat] = f2bf(rv * e1);
      rwg[t * KD + lk] = f2bf(rv * e1 * eoff);  // r * exp(cum) for scan_inter
      ki_s[nat] = f2bf(kv * __expf(myoff - c - wl[tt]));
      vb8[tt & 7] = (short)f2bf(vvv);
      darr[tt & 7] = rv * uk * kv;
      c += wl[tt];
      if ((tt & 7) == 7) {
        const int g = t >> 3;
        *(short8*)&vT_s[lk * TC + ((g ^ (lk & 7)) << 3)] = vb8;
        // batched butterfly: 8 independent reductions
        #pragma unroll
        for (int o = 32; o > 0; o >>= 1)
          #pragma unroll
          for (int q = 0; q < 8; ++q) darr[q] += __shfl_xor(darr[q], o, 64);
        if (lk == 0) {
          short8 dpk;
          #pragma unroll
          for (int q = 0; q < 8; ++q) dpk[q] = (short)f2bf(darr[q]);
          *(short8*)&diagg[g * 8] = dpk;
        }
      }
    }
  }
  __syncthreads();

  const int lane = tid & 63, quad = lane >> 4, l16 = lane & 15;

  // ---- wkv = (ki * w_inter)^T @ v -> bf16 ws (A-frags via scalar LDS reads) ----
  {
    f32x4 acc[4] = {{0,0,0,0},{0,0,0,0},{0,0,0,0},{0,0,0,0}};
    const int kdg = wv * 2 + (l16 >> 3), kd7 = l16 & 7;
    #pragma unroll
    for (int ks = 0; ks < 4; ++ks) {
      short8 a;
      #pragma unroll
      for (int j = 0; j < 8; ++j) {
        const int t = ks * 32 + quad * 8 + j;
        a[j] = (short)ki_s[t * KD + (((kdg ^ (t & 7) ^ ((t >> 3) & 7)) << 3) + kd7)];
      }
      #pragma unroll
      for (int nn = 0; nn < 4; ++nn) {
        const int vd = nn * 16 + l16;
        short8 b = *(const short8*)&vT_s[vd * TC + (((ks * 4 + quad) ^ (vd & 7)) << 3)];
        acc[nn] = __builtin_amdgcn_mfma_f32_16x16x32_bf16(a, b, acc[nn], 0, 0, 0);
      }
    }
    float wso[4];
    #pragma unroll
    for (int reg = 0; reg < 4; ++reg) wso[reg] = __shfl(wsoff_own, wv * 16 + quad * 4 + reg, 64);
    unsigned short* wkvg = wkv_u16 + ((size_t)bh * N + n) * (KD * KD);
    #pragma unroll
    for (int nn = 0; nn < 4; ++nn)
      #pragma unroll
      for (int reg = 0; reg < 4; ++reg)
        wkvg[(wv * 16 + quad * 4 + reg) * KD + nn * 16 + l16] = f2bf(acc[nn][reg] * wso[reg]);
  }

  // ---- fused A^T tiles + out = A@v (per-wave, no block sync) ----
  #pragma unroll
  for (int half = 0; half < 2; ++half) {
    const int ib = half ? (7 - wv) : wv;
    const int i0 = ib * 16;
    const int irow = i0 + l16;
    const int rsw = (irow & 7) ^ ((irow >> 3) & 7);
    short8 b0 = *(const short8*)&rd_s[irow * KD + ((quad ^ rsw) << 3)];
    short8 b1 = *(const short8*)&rd_s[irow * KD + (((4 + quad) ^ rsw) << 3)];
    const float diag_i = bf2f(diagg[irow]);
    f32x4 oacc[4] = {{0,0,0,0},{0,0,0,0},{0,0,0,0},{0,0,0,0}};
    const int npairs = (ib + 2) >> 1;
    unsigned short* astw = Ast + wv * 640;
    for (int jp = 0; jp < npairs; ++jp) {
      #pragma unroll
      for (int jj = 0; jj < 2; ++jj) {
        const int j = jp * 2 + jj;
        short4_t pk;
        if (j <= ib) {
          const int jrow = j * 16 + l16;
          const int jsw = (jrow & 7) ^ ((jrow >> 3) & 7);
          short8 a0 = *(const short8*)&ki_s[jrow * KD + ((quad ^ jsw) << 3)];
          short8 a1 = *(const short8*)&ki_s[jrow * KD + (((4 + quad) ^ jsw) << 3)];
          f32x4 at = {0, 0, 0, 0};
          at = __builtin_amdgcn_mfma_f32_16x16x32_bf16(a0, b0, at, 0, 0, 0);
          at = __builtin_amdgcn_mfma_f32_16x16x32_bf16(a1, b1, at, 0, 0, 0);
          #pragma unroll
          for (int reg = 0; reg < 4; ++reg) {
            const int je = j * 16 + quad * 4 + reg;
            float val = at[reg];
            if (j == ib) val = (je < irow) ? val : ((je == irow) ? diag_i : 0.f);
            pk[reg] = (short)f2bf(val);
          }
        } else {
          pk = (short4_t)0;  // guard half for even ib
        }
        *(short4_t*)&astw[l16 * 40 + jj * 16 + quad * 4] = pk;
      }
      short8 af = *(const short8*)&astw[l16 * 40 + quad * 8];
      #pragma unroll
      for (int nn = 0; nn < 4; ++nn) {
        const int vd = nn * 16 + l16;
        short8 bv = *(const short8*)&vT_s[vd * TC + (((jp * 4 + quad) ^ (vd & 7)) << 3)];
        oacc[nn] = __builtin_amdgcn_mfma_f32_16x16x32_bf16(af, bv, oacc[nn], 0, 0, 0);
      }
    }
    float* og = out + base;
    #pragma unroll
    for (int nn = 0; nn < 4; ++nn)
      #pragma unroll
      for (int reg = 0; reg < 4; ++reg)
        og[(i0 + quad * 4 + reg) * KD + nn * 16 + l16] = oacc[nn][reg];
  }
}

// ---------------------------------------------------------------------------
// K2 (fused scan+apply, fully parallel): block = (bh, n), BH*N = 1024 blocks.
// Each block recomputes S_n itself by scanning wkv[0..n-1] (L2/L3-hot: wkv
// is only 8.4 MB total) -> every block independent: no serial scan kernel,
// no states round-trip, one fewer launch. Scan is bit-identical f32 fma to
// the old K2a (same expression, same order). Then out += rw @ S_n with the
// accumulator repacked through a 17 KB LDS half-tile so the global RMW is
// float4 both ways (4x fewer memory instrs, 1 KB/wave/instr).
// LDS 25,600 B -> 6 blocks/CU (24 waves/CU).
// ---------------------------------------------------------------------------
__global__ __launch_bounds__(256, 6)
void rwkv_scan_apply(const unsigned short* __restrict__ wkv_u16,
                     const float* __restrict__ wse_ws,
                     const float* __restrict__ st_in,
                     const unsigned short* __restrict__ rw_u16,
                     float* __restrict__ out, float* __restrict__ final_out, int N) {
  __shared__ alignas(16) unsigned short sT[KD * KD];    // 8 KB: S_n^T swizzled bf16
  __shared__ alignas(16) float obuf[64 * 68];           // 17,408 B: half-tile f32, stride 68

  const int bid = blockIdx.x;
  const int n = bid % N, bh = bid / N;
  const int tid = threadIdx.x;

  // ---- per-thread prefix scan: thread owns (kd = tid>>2, vd = v0..v0+15) ----
  const int kd = tid >> 2, v0 = (tid & 3) * 16;
  const size_t sbase = (size_t)bh * (KD * KD);
  float s[16];
  #pragma unroll
  for (int i = 0; i < 16; i += 4)
    *(f32x4*)&s[i] = *(const f32x4*)&st_in[sbase + kd * KD + v0 + i];

  const float* wseb = wse_ws + (size_t)bh * N * KD + kd;
  const unsigned short* wkvb = wkv_u16 + (size_t)bh * N * (KD * KD) + kd * KD + v0;

  {
    float e_c = 0.f; short8 x0_c = {0}, x1_c = {0};
    if (n > 0) {
      e_c = wseb[0];
      x0_c = *(const short8*)&wkvb[0];
      x1_c = *(const short8*)&wkvb[8];
    }
    for (int j = 0; j < n; ++j) {
      const float e = e_c; const short8 x0 = x0_c, x1 = x1_c;
      if (j + 1 < n) {
        e_c = wseb[(size_t)(j + 1) * KD];
        x0_c = *(const short8*)&wkvb[(size_t)(j + 1) * (KD * KD)];
        x1_c = *(const short8*)&wkvb[(size_t)(j + 1) * (KD * KD) + 8];
      }
      #pragma unroll
      for (int i = 0; i < 8; ++i) {
        s[i]     = s[i]     * e + bf2f((unsigned short)x0[i]);
        s[i + 8] = s[i + 8] * e + bf2f((unsigned short)x1[i]);
      }
    }
  }

  // ---- stage S_n^T into LDS (transpose + swizzle, from registers) ----
  {
    const int g = kd >> 3, k7 = kd & 7;
    #pragma unroll
    for (int i = 0; i < 16; ++i) {
      const int vd = v0 + i;
      sT[vd * KD + (((g ^ (vd & 7)) << 3) | k7)] = f2bf(s[i]);
    }
  }

  // ---- final state: only the n == N-1 blocks do one more step + write ----
  if (n == N - 1) {
    const float e = wseb[(size_t)(N - 1) * KD];
    const short8 x0 = *(const short8*)&wkvb[(size_t)(N - 1) * (KD * KD)];
    const short8 x1 = *(const short8*)&wkvb[(size_t)(N - 1) * (KD * KD) + 8];
    #pragma unroll
    for (int i = 0; i < 8; ++i) {
      s[i]     = s[i]     * e + bf2f((unsigned short)x0[i]);
      s[i + 8] = s[i + 8] * e + bf2f((unsigned short)x1[i]);
    }
    #pragma unroll
    for (int i = 0; i < 16; i += 4)
      *(f32x4*)&final_out[sbase + kd * KD + v0 + i] = *(const f32x4*)&s[i];
  }
  __syncthreads();

  // ---- out += rw @ S_n, epilogue via LDS half-tile for float4 RMW ----
  const int lane = tid & 63, wv = tid >> 6, quad = lane >> 4, l16 = lane & 15;
  const unsigned short* rwg = rw_u16 + ((size_t)bh * N + n) * (TC * KD);
  float* og = out + ((size_t)bh * N + n) * (TC * KD);
  #pragma unroll
  for (int half = 0; half < 2; ++half) {
    const int mt = wv + half * 4;
    const int trow = mt * 16 + l16;
    short8 a0 = *(const short8*)&rwg[trow * KD + quad * 8];
    short8 a1 = *(const short8*)&rwg[trow * KD + 32 + quad * 8];
    const int lr0 = (mt - half * 4) * 16 + quad * 4;   // local row base in obuf
    #pragma unroll
    for (int nn = 0; nn < 4; ++nn) {
      const int vd = nn * 16 + l16;
      short8 b0 = *(const short8*)&sT[vd * KD + ((quad ^ (vd & 7)) << 3)];
      short8 b1 = *(const short8*)&sT[vd * KD + (((4 + quad) ^ (vd & 7)) << 3)];
      f32x4 acc = {0, 0, 0, 0};
      acc = __builtin_amdgcn_mfma_f32_16x16x32_bf16(a0, b0, acc, 0, 0, 0);
      acc = __builtin_amdgcn_mfma_f32_16x16x32_bf16(a1, b1, acc, 0, 0, 0);
      #pragma unroll
      for (int reg = 0; reg < 4; ++reg)
        obuf[(lr0 + reg) * 68 + nn * 16 + l16] = acc[reg];
    }
    __syncthreads();
    // float4 RMW of 64 global rows (16 KB): 4 float4s per thread,
    // 1 KB contiguous per wave per instruction.
    {
      float* ogh = og + half * 64 * KD;
      #pragma unroll
      for (int i = 0; i < 4; ++i) {
        const int f = tid + i * 256;            // float4 index 0..1023
        const int row = f >> 4, c4 = (f & 15) * 4;
        f32x4 l = *(const f32x4*)&obuf[row * 68 + c4];
        f32x4 gv = *(const f32x4*)&ogh[row * KD + c4];
        gv += l;
        *(f32x4*)&ogh[row * KD + c4] = gv;
      }
    }
    __syncthreads();
  }
}

// ---------------------------------------------------------------------------
// Workspace (~24.75 MB): [wkv u16: BH*N*K*K][wse f32: BH*N*K]
//                        [rw u16: BH*T*K][diag u16: BH*N*TC]
// ---------------------------------------------------------------------------
extern "C" void kernel_launch(void* const* d_in, const int* in_sizes, int n_in,
                              void* d_out, int out_size, void* d_ws, size_t ws_size,
                              hipStream_t stream) {
  const float* r = (const float*)d_in[0];
  const float* k = (const float*)d_in[1];
  const float* v = (const float*)d_in[2];
  const float* w = (const float*)d_in[3];
  const float* u = (const float*)d_in[4];
  const float* st0 = (const float*)d_in[5];
  float* out = (float*)d_out;

  const int BH = in_sizes[5] / (KD * KD);  // 64
  const int H = in_sizes[4] / KD;          // 16
  const int T = in_sizes[0] / (BH * KD);   // 2048
  const int N = T / TC;                    // 16

  unsigned short* wkv_u16 = (unsigned short*)d_ws;
  float* wse_ws = (float*)(wkv_u16 + (size_t)BH * N * KD * KD);
  unsigned short* rw_u16 = (unsigned short*)(wse_ws + (size_t)BH * N * KD);
  unsigned short* diag_u16 = rw_u16 + (size_t)BH * T * KD;
  float* final_out = out + (size_t)in_sizes[0];

  rwkv_intra_mfma<<<BH * N, 256, 0, stream>>>(r, k, v, w, u, out, wkv_u16, wse_ws,
                                              rw_u16, diag_u16, H, N);
  rwkv_scan_apply<<<BH * N, 256, 0, stream>>>(wkv_u16, wse_ws, st0, rw_u16,
                                              out, final_out, N);
}

// Round 3
// 198.252 us; speedup vs baseline: 1.0357x; 1.0012x over previous
//
#include <hip/hip_runtime.h>

#define TC 128
#define KD 64
#define WLOG_MIN (-5.2983174f)   // ln(0.005)

typedef __attribute__((ext_vector_type(8))) short short8;
typedef __attribute__((ext_vector_type(4))) short short4_t;
typedef __attribute__((ext_vector_type(4))) float f32x4;

__device__ __forceinline__ unsigned short f2bf(float x) {
  union { float f; unsigned int u; } c; c.f = x;
  unsigned int u = c.u + 0x7fffu + ((c.u >> 16) & 1u);   // RNE
  return (unsigned short)(u >> 16);
}
__device__ __forceinline__ float bf2f(unsigned short x) {
  union { unsigned int u; float f; } c; c.u = ((unsigned int)x) << 16; return c.f;
}

// rd_s/ki_s swizzle: element (t,kd) stored at t*64 + (slot<<3 | kd&7),
// slot = (kd>>3) ^ (t&7) ^ ((t>>3)&7).  b128 granule-q reads use
// slot = q ^ (t&7) ^ ((t>>3)&7).  vT/sT swizzle: slot = g ^ (row&7).

// ---------------------------------------------------------------------------
// K1: per-(b,h,chunk), 512 threads / 8 waves. Each wave owns a 16-timestep
// segment. LDS 59,392 B -> 2 blocks/CU at 512 thr = 16 waves/CU resident,
// and 1024 blocks / 512 resident = exactly 2 full rounds (no partial tail;
// the old 256-thread version ran 3 blocks/CU -> 1.33 rounds with a
// 4-waves/CU tail round, avg occupancy 18%).
// ---------------------------------------------------------------------------
__global__ __launch_bounds__(512, 4)
void rwkv_intra_mfma(const float* __restrict__ rr, const float* __restrict__ kk_,
                     const float* __restrict__ vv, const float* __restrict__ ww,
                     const float* __restrict__ uu, float* __restrict__ out,
                     unsigned short* __restrict__ wkv_u16, float* __restrict__ wse_ws,
                     unsigned short* __restrict__ rw_u16, unsigned short* __restrict__ diag_u16,
                     int H, int N) {
  __shared__ alignas(16) unsigned short rd_s[TC * KD];
  __shared__ alignas(16) unsigned short ki_s[TC * KD];
  __shared__ alignas(16) unsigned short vT_s[KD * TC];
  __shared__ alignas(16) unsigned char su_raw[10240];  // union: segtot f32[8][64] | Ast u16[8][640]
  float* segtot = (float*)su_raw;
  unsigned short* Ast = (unsigned short*)su_raw;

  const int bid = blockIdx.x;
  const int n = bid % N, bh = bid / N, h = bh % H;
  const size_t base = ((size_t)bh * N + n) * (TC * KD);
  const float *rg = rr + base, *kg = kk_ + base, *vg = vv + base, *wg = ww + base;
  unsigned short* diagg = diag_u16 + (size_t)bid * TC;

  const int tid = threadIdx.x;
  const int lk = tid & 63;    // k-column during staging (= lane)
  const int wv = tid >> 6;    // wave id = 16-row t-segment (0..7)

  // ---- pass 1: w (regs) + segment totals ----
  float wl[16];
  {
    float c = 0.f;
    #pragma unroll
    for (int tt = 0; tt < 16; ++tt) {
      wl[tt] = fmaxf(wg[(wv * 16 + tt) * KD + lk], WLOG_MIN);
      c += wl[tt];
    }
    segtot[wv * 64 + lk] = c;
  }
  __syncthreads();
  float segofs = 0.f, myoff = 0.f, wsum = 0.f;
  #pragma unroll
  for (int i = 0; i < 8; ++i) {
    const float si = segtot[i * 64 + lk];
    if (i < wv) segofs += si;
    if (i < 4) myoff += si;     // cum at t = Tc/2
    wsum += si;
  }
  const float wsoff_own = __expf(wsum - myoff);   // kept in reg (segtot gets clobbered by Ast)
  if (wv == 0) wse_ws[((size_t)bh * N + n) * KD + lk] = __expf(wsum);
  const float eoff = __expf(myoff);

  // ---- pass 2: staging ----
  {
    float c = segofs;
    const float uk = uu[h * KD + lk];
    unsigned short* rwg = rw_u16 + base;
    short8 vb8;
    float darr[8];
    #pragma unroll
    for (int tt = 0; tt < 16; ++tt) {
      const int t = wv * 16 + tt;
      float rv = rg[t * KD + lk], kv = kg[t * KD + lk], vvv = vg[t * KD + lk];
      const int slot = (lk >> 3) ^ (t & 7) ^ ((t >> 3) & 7);
      const int nat = t * KD + (slot << 3) + (lk & 7);
      float e1 = __expf(c - myoff);
      rd_s[nat] = f2bf(rv * e1);
      rwg[t * KD + lk] = f2bf(rv * e1 * eoff);  // r * exp(cum) for scan_inter
      ki_s[nat] = f2bf(kv * __expf(myoff - c - wl[tt]));
      vb8[tt & 7] = (short)f2bf(vvv);
      darr[tt & 7] = rv * uk * kv;
      c += wl[tt];
      if ((tt & 7) == 7) {
        const int g = t >> 3;
        *(short8*)&vT_s[lk * TC + ((g ^ (lk & 7)) << 3)] = vb8;
        // batched butterfly: 8 independent reductions
        #pragma unroll
        for (int o = 32; o > 0; o >>= 1)
          #pragma unroll
          for (int q = 0; q < 8; ++q) darr[q] += __shfl_xor(darr[q], o, 64);
        if (lk == 0) {
          short8 dpk;
          #pragma unroll
          for (int q = 0; q < 8; ++q) dpk[q] = (short)f2bf(darr[q]);
          *(short8*)&diagg[g * 8] = dpk;
        }
      }
    }
  }
  __syncthreads();

  const int lane = tid & 63, quad = lane >> 4, l16 = lane & 15;

  // ---- wkv = (ki * w_inter)^T @ v -> bf16 ws (2 of 16 tiles per wave) ----
  {
    const int kt = wv >> 1;             // kd-tile 0..3
    const int nb = (wv & 1) * 2;        // vd-tile base: {0,1} or {2,3}
    f32x4 acc[2] = {{0,0,0,0},{0,0,0,0}};
    const int kdg = kt * 2 + (l16 >> 3), kd7 = l16 & 7;
    #pragma unroll
    for (int ks = 0; ks < 4; ++ks) {
      short8 a;
      #pragma unroll
      for (int j = 0; j < 8; ++j) {
        const int t = ks * 32 + quad * 8 + j;
        a[j] = (short)ki_s[t * KD + (((kdg ^ (t & 7) ^ ((t >> 3) & 7)) << 3) + kd7)];
      }
      #pragma unroll
      for (int nn = 0; nn < 2; ++nn) {
        const int vd = (nb + nn) * 16 + l16;
        short8 b = *(const short8*)&vT_s[vd * TC + (((ks * 4 + quad) ^ (vd & 7)) << 3)];
        acc[nn] = __builtin_amdgcn_mfma_f32_16x16x32_bf16(a, b, acc[nn], 0, 0, 0);
      }
    }
    float wso[4];
    #pragma unroll
    for (int reg = 0; reg < 4; ++reg) wso[reg] = __shfl(wsoff_own, kt * 16 + quad * 4 + reg, 64);
    unsigned short* wkvg = wkv_u16 + ((size_t)bh * N + n) * (KD * KD);
    #pragma unroll
    for (int nn = 0; nn < 2; ++nn)
      #pragma unroll
      for (int reg = 0; reg < 4; ++reg)
        wkvg[(kt * 16 + quad * 4 + reg) * KD + (nb + nn) * 16 + l16] = f2bf(acc[nn][reg] * wso[reg]);
  }

  // ---- fused A^T tiles + out = A@v (one ib per wave, no block sync) ----
  {
    const int ib = wv;
    const int i0 = ib * 16;
    const int irow = i0 + l16;
    const int rsw = (irow & 7) ^ ((irow >> 3) & 7);
    short8 b0 = *(const short8*)&rd_s[irow * KD + ((quad ^ rsw) << 3)];
    short8 b1 = *(const short8*)&rd_s[irow * KD + (((4 + quad) ^ rsw) << 3)];
    const float diag_i = bf2f(diagg[irow]);
    f32x4 oacc[4] = {{0,0,0,0},{0,0,0,0},{0,0,0,0},{0,0,0,0}};
    const int npairs = (ib + 2) >> 1;
    unsigned short* astw = Ast + wv * 640;
    for (int jp = 0; jp < npairs; ++jp) {
      #pragma unroll
      for (int jj = 0; jj < 2; ++jj) {
        const int j = jp * 2 + jj;
        short4_t pk;
        if (j <= ib) {
          const int jrow = j * 16 + l16;
          const int jsw = (jrow & 7) ^ ((jrow >> 3) & 7);
          short8 a0 = *(const short8*)&ki_s[jrow * KD + ((quad ^ jsw) << 3)];
          short8 a1 = *(const short8*)&ki_s[jrow * KD + (((4 + quad) ^ jsw) << 3)];
          f32x4 at = {0, 0, 0, 0};
          at = __builtin_amdgcn_mfma_f32_16x16x32_bf16(a0, b0, at, 0, 0, 0);
          at = __builtin_amdgcn_mfma_f32_16x16x32_bf16(a1, b1, at, 0, 0, 0);
          #pragma unroll
          for (int reg = 0; reg < 4; ++reg) {
            const int je = j * 16 + quad * 4 + reg;
            float val = at[reg];
            if (j == ib) val = (je < irow) ? val : ((je == irow) ? diag_i : 0.f);
            pk[reg] = (short)f2bf(val);
          }
        } else {
          pk = (short4_t)0;  // guard half for even ib
        }
        *(short4_t*)&astw[l16 * 40 + jj * 16 + quad * 4] = pk;
      }
      short8 af = *(const short8*)&astw[l16 * 40 + quad * 8];
      #pragma unroll
      for (int nn = 0; nn < 4; ++nn) {
        const int vd = nn * 16 + l16;
        short8 bv = *(const short8*)&vT_s[vd * TC + (((jp * 4 + quad) ^ (vd & 7)) << 3)];
        oacc[nn] = __builtin_amdgcn_mfma_f32_16x16x32_bf16(af, bv, oacc[nn], 0, 0, 0);
      }
    }
    float* og = out + base;
    #pragma unroll
    for (int nn = 0; nn < 4; ++nn)
      #pragma unroll
      for (int reg = 0; reg < 4; ++reg)
        og[(i0 + quad * 4 + reg) * KD + nn * 16 + l16] = oacc[nn][reg];
  }
}

// ---------------------------------------------------------------------------
// K2 (fused scan+apply, fully parallel): block = (bh, n), BH*N = 1024 blocks.
// Each block recomputes S_n itself by scanning wkv[0..n-1] (L2/L3-hot: wkv
// is only 8.4 MB total). Then out += rw @ S_n with the accumulator repacked
// through a 17 KB LDS half-tile so the global RMW is float4 both ways.
// LDS 25,600 B -> 6 blocks/CU (24 waves/CU). (unchanged)
// ---------------------------------------------------------------------------
__global__ __launch_bounds__(256, 6)
void rwkv_scan_apply(const unsigned short* __restrict__ wkv_u16,
                     const float* __restrict__ wse_ws,
                     const float* __restrict__ st_in,
                     const unsigned short* __restrict__ rw_u16,
                     float* __restrict__ out, float* __restrict__ final_out, int N) {
  __shared__ alignas(16) unsigned short sT[KD * KD];    // 8 KB: S_n^T swizzled bf16
  __shared__ alignas(16) float obuf[64 * 68];           // 17,408 B: half-tile f32, stride 68

  const int bid = blockIdx.x;
  const int n = bid % N, bh = bid / N;
  const int tid = threadIdx.x;

  // ---- per-thread prefix scan: thread owns (kd = tid>>2, vd = v0..v0+15) ----
  const int kd = tid >> 2, v0 = (tid & 3) * 16;
  const size_t sbase = (size_t)bh * (KD * KD);
  float s[16];
  #pragma unroll
  for (int i = 0; i < 16; i += 4)
    *(f32x4*)&s[i] = *(const f32x4*)&st_in[sbase + kd * KD + v0 + i];

  const float* wseb = wse_ws + (size_t)bh * N * KD + kd;
  const unsigned short* wkvb = wkv_u16 + (size_t)bh * N * (KD * KD) + kd * KD + v0;

  {
    float e_c = 0.f; short8 x0_c = {0}, x1_c = {0};
    if (n > 0) {
      e_c = wseb[0];
      x0_c = *(const short8*)&wkvb[0];
      x1_c = *(const short8*)&wkvb[8];
    }
    for (int j = 0; j < n; ++j) {
      const float e = e_c; const short8 x0 = x0_c, x1 = x1_c;
      if (j + 1 < n) {
        e_c = wseb[(size_t)(j + 1) * KD];
        x0_c = *(const short8*)&wkvb[(size_t)(j + 1) * (KD * KD)];
        x1_c = *(const short8*)&wkvb[(size_t)(j + 1) * (KD * KD) + 8];
      }
      #pragma unroll
      for (int i = 0; i < 8; ++i) {
        s[i]     = s[i]     * e + bf2f((unsigned short)x0[i]);
        s[i + 8] = s[i + 8] * e + bf2f((unsigned short)x1[i]);
      }
    }
  }

  // ---- stage S_n^T into LDS (transpose + swizzle, from registers) ----
  {
    const int g = kd >> 3, k7 = kd & 7;
    #pragma unroll
    for (int i = 0; i < 16; ++i) {
      const int vd = v0 + i;
      sT[vd * KD + (((g ^ (vd & 7)) << 3) | k7)] = f2bf(s[i]);
    }
  }

  // ---- final state: only the n == N-1 blocks do one more step + write ----
  if (n == N - 1) {
    const float e = wseb[(size_t)(N - 1) * KD];
    const short8 x0 = *(const short8*)&wkvb[(size_t)(N - 1) * (KD * KD)];
    const short8 x1 = *(const short8*)&wkvb[(size_t)(N - 1) * (KD * KD) + 8];
    #pragma unroll
    for (int i = 0; i < 8; ++i) {
      s[i]     = s[i]     * e + bf2f((unsigned short)x0[i]);
      s[i + 8] = s[i + 8] * e + bf2f((unsigned short)x1[i]);
    }
    #pragma unroll
    for (int i = 0; i < 16; i += 4)
      *(f32x4*)&final_out[sbase + kd * KD + v0 + i] = *(const f32x4*)&s[i];
  }
  __syncthreads();

  // ---- out += rw @ S_n, epilogue via LDS half-tile for float4 RMW ----
  const int lane = tid & 63, wv = tid >> 6, quad = lane >> 4, l16 = lane & 15;
  const unsigned short* rwg = rw_u16 + ((size_t)bh * N + n) * (TC * KD);
  float* og = out + ((size_t)bh * N + n) * (TC * KD);
  #pragma unroll
  for (int half = 0; half < 2; ++half) {
    const int mt = wv + half * 4;
    const int trow = mt * 16 + l16;
    short8 a0 = *(const short8*)&rwg[trow * KD + quad * 8];
    short8 a1 = *(const short8*)&rwg[trow * KD + 32 + quad * 8];
    const int lr0 = (mt - half * 4) * 16 + quad * 4;   // local row base in obuf
    #pragma unroll
    for (int nn = 0; nn < 4; ++nn) {
      const int vd = nn * 16 + l16;
      short8 b0 = *(const short8*)&sT[vd * KD + ((quad ^ (vd & 7)) << 3)];
      short8 b1 = *(const short8*)&sT[vd * KD + (((4 + quad) ^ (vd & 7)) << 3)];
      f32x4 acc = {0, 0, 0, 0};
      acc = __builtin_amdgcn_mfma_f32_16x16x32_bf16(a0, b0, acc, 0, 0, 0);
      acc = __builtin_amdgcn_mfma_f32_16x16x32_bf16(a1, b1, acc, 0, 0, 0);
      #pragma unroll
      for (int reg = 0; reg < 4; ++reg)
        obuf[(lr0 + reg) * 68 + nn * 16 + l16] = acc[reg];
    }
    __syncthreads();
    // float4 RMW of 64 global rows (16 KB): 4 float4s per thread,
    // 1 KB contiguous per wave per instruction.
    {
      float* ogh = og + half * 64 * KD;
      #pragma unroll
      for (int i = 0; i < 4; ++i) {
        const int f = tid + i * 256;            // float4 index 0..1023
        const int row = f >> 4, c4 = (f & 15) * 4;
        f32x4 l = *(const f32x4*)&obuf[row * 68 + c4];
        f32x4 gv = *(const f32x4*)&ogh[row * KD + c4];
        gv += l;
        *(f32x4*)&ogh[row * KD + c4] = gv;
      }
    }
    __syncthreads();
  }
}

// ---------------------------------------------------------------------------
// Workspace (~24.75 MB): [wkv u16: BH*N*K*K][wse f32: BH*N*K]
//                        [rw u16: BH*T*K][diag u16: BH*N*TC]
// ---------------------------------------------------------------------------
extern "C" void kernel_launch(void* const* d_in, const int* in_sizes, int n_in,
                              void* d_out, int out_size, void* d_ws, size_t ws_size,
                              hipStream_t stream) {
  const float* r = (const float*)d_in[0];
  const float* k = (const float*)d_in[1];
  const float* v = (const float*)d_in[2];
  const float* w = (const float*)d_in[3];
  const float* u = (const float*)d_in[4];
  const float* st0 = (const float*)d_in[5];
  float* out = (float*)d_out;

  const int BH = in_sizes[5] / (KD * KD);  // 64
  const int H = in_sizes[4] / KD;          // 16
  const int T = in_sizes[0] / (BH * KD);   // 2048
  const int N = T / TC;                    // 16

  unsigned short* wkv_u16 = (unsigned short*)d_ws;
  float* wse_ws = (float*)(wkv_u16 + (size_t)BH * N * KD * KD);
  unsigned short* rw_u16 = (unsigned short*)(wse_ws + (size_t)BH * N * KD);
  unsigned short* diag_u16 = rw_u16 + (size_t)BH * T * KD;
  float* final_out = out + (size_t)in_sizes[0];

  rwkv_intra_mfma<<<BH * N, 512, 0, stream>>>(r, k, v, w, u, out, wkv_u16, wse_ws,
                                              rw_u16, diag_u16, H, N);
  rwkv_scan_apply<<<BH * N, 256, 0, stream>>>(wkv_u16, wse_ws, st0, rw_u16,
                                              out, final_out, N);
}

// Round 4
// 197.448 us; speedup vs baseline: 1.0399x; 1.0041x over previous
//
#include <hip/hip_runtime.h>

#define TC 128
#define KD 64
#define WLOG_MIN (-5.2983174f)   // ln(0.005)

typedef __attribute__((ext_vector_type(8))) short short8;
typedef __attribute__((ext_vector_type(4))) short short4_t;
typedef __attribute__((ext_vector_type(4))) float f32x4;

__device__ __forceinline__ unsigned short f2bf(float x) {
  union { float f; unsigned int u; } c; c.f = x;
  unsigned int u = c.u + 0x7fffu + ((c.u >> 16) & 1u);   // RNE
  return (unsigned short)(u >> 16);
}
__device__ __forceinline__ float bf2f(unsigned short x) {
  union { unsigned int u; float f; } c; c.u = ((unsigned int)x) << 16; return c.f;
}

// rd_s/ki_s swizzle: element (t,kd) stored at t*64 + (slot<<3 | kd&7),
// slot = (kd>>3) ^ (t&7) ^ ((t>>3)&7).  b128 granule-q reads use
// slot = q ^ (t&7) ^ ((t>>3)&7).  vT/kiT swizzle: slot = g ^ (row&7).

// ---------------------------------------------------------------------------
// K1: per-(b,h,chunk), 512 threads / 8 waves, 16-timestep segment per wave.
// This round: (a) issue-early batched loads — all 64 w/r/k/v scalar loads per
// thread are in flight before the pass-1 barrier (prev: compiler at 52 VGPR
// issued a few at a time, fully latency-exposed); (b) kiT_s transposed copy
// (built like vT_s) turns the wkv A-frag gather from 32 ds_read_u16/thread
// into 4 ds_read_b128/thread. LDS 75,776 B -> still 2 blocks/CU.
// ---------------------------------------------------------------------------
__global__ __launch_bounds__(512, 4)
void rwkv_intra_mfma(const float* __restrict__ rr, const float* __restrict__ kk_,
                     const float* __restrict__ vv, const float* __restrict__ ww,
                     const float* __restrict__ uu, float* __restrict__ out,
                     unsigned short* __restrict__ wkv_u16, float* __restrict__ wse_ws,
                     unsigned short* __restrict__ rw_u16, unsigned short* __restrict__ diag_u16,
                     int H, int N) {
  __shared__ alignas(16) unsigned short rd_s[TC * KD];
  __shared__ alignas(16) unsigned short ki_s[TC * KD];
  __shared__ alignas(16) unsigned short vT_s[KD * TC];
  __shared__ alignas(16) unsigned short kiT_s[KD * TC];
  __shared__ alignas(16) unsigned char su_raw[10240];  // union: segtot f32[8][64] | Ast u16[8][640]
  float* segtot = (float*)su_raw;
  unsigned short* Ast = (unsigned short*)su_raw;

  const int bid = blockIdx.x;
  const int n = bid % N, bh = bid / N, h = bh % H;
  const size_t base = ((size_t)bh * N + n) * (TC * KD);
  const float *rg = rr + base, *kg = kk_ + base, *vg = vv + base, *wg = ww + base;
  unsigned short* diagg = diag_u16 + (size_t)bid * TC;

  const int tid = threadIdx.x;
  const int lk = tid & 63;    // k-column during staging (= lane)
  const int wv = tid >> 6;    // wave id = 16-row t-segment (0..7)

  // ---- issue-early: ALL global loads for this thread, before any compute ----
  float wl[16];
  #pragma unroll
  for (int tt = 0; tt < 16; ++tt)
    wl[tt] = wg[(wv * 16 + tt) * KD + lk];
  float rv_[16], kv_[16], vv_[16];
  #pragma unroll
  for (int tt = 0; tt < 16; ++tt) {
    const int t = wv * 16 + tt;
    rv_[tt] = rg[t * KD + lk];
    kv_[tt] = kg[t * KD + lk];
    vv_[tt] = vg[t * KD + lk];
  }
  const float uk = uu[h * KD + lk];

  // ---- pass 1: w clamp + segment totals (r/k/v loads still in flight) ----
  {
    float c = 0.f;
    #pragma unroll
    for (int tt = 0; tt < 16; ++tt) {
      wl[tt] = fmaxf(wl[tt], WLOG_MIN);
      c += wl[tt];
    }
    segtot[wv * 64 + lk] = c;
  }
  __syncthreads();
  float segofs = 0.f, myoff = 0.f, wsum = 0.f;
  #pragma unroll
  for (int i = 0; i < 8; ++i) {
    const float si = segtot[i * 64 + lk];
    if (i < wv) segofs += si;
    if (i < 4) myoff += si;     // cum at t = Tc/2
    wsum += si;
  }
  const float wsoff_own = __expf(wsum - myoff);   // kept in reg (segtot gets clobbered by Ast)
  if (wv == 0) wse_ws[((size_t)bh * N + n) * KD + lk] = __expf(wsum);
  const float eoff = __expf(myoff);

  // ---- pass 2: staging (pure compute + LDS/global stores) ----
  {
    float c = segofs;
    unsigned short* rwg = rw_u16 + base;
    short8 vb8, kib8;
    float darr[8];
    #pragma unroll
    for (int tt = 0; tt < 16; ++tt) {
      const int t = wv * 16 + tt;
      const float rv = rv_[tt], kv = kv_[tt], vvv = vv_[tt];
      const int slot = (lk >> 3) ^ (t & 7) ^ ((t >> 3) & 7);
      const int nat = t * KD + (slot << 3) + (lk & 7);
      float e1 = __expf(c - myoff);
      rd_s[nat] = f2bf(rv * e1);
      rwg[t * KD + lk] = f2bf(rv * e1 * eoff);  // r * exp(cum) for scan_inter
      const unsigned short kiv = f2bf(kv * __expf(myoff - c - wl[tt]));
      ki_s[nat] = kiv;
      kib8[tt & 7] = (short)kiv;
      vb8[tt & 7] = (short)f2bf(vvv);
      darr[tt & 7] = rv * uk * kv;
      c += wl[tt];
      if ((tt & 7) == 7) {
        const int g = t >> 3;
        *(short8*)&vT_s[lk * TC + ((g ^ (lk & 7)) << 3)] = vb8;
        *(short8*)&kiT_s[lk * TC + ((g ^ (lk & 7)) << 3)] = kib8;
        // batched butterfly: 8 independent reductions
        #pragma unroll
        for (int o = 32; o > 0; o >>= 1)
          #pragma unroll
          for (int q = 0; q < 8; ++q) darr[q] += __shfl_xor(darr[q], o, 64);
        if (lk == 0) {
          short8 dpk;
          #pragma unroll
          for (int q = 0; q < 8; ++q) dpk[q] = (short)f2bf(darr[q]);
          *(short8*)&diagg[g * 8] = dpk;
        }
      }
    }
  }
  __syncthreads();

  const int lane = tid & 63, quad = lane >> 4, l16 = lane & 15;

  // ---- wkv = (ki * w_inter)^T @ v -> bf16 ws (A-frags now b128 from kiT) ----
  {
    const int kt = wv >> 1;             // kd-tile 0..3
    const int nb = (wv & 1) * 2;        // vd-tile base: {0,1} or {2,3}
    f32x4 acc[2] = {{0,0,0,0},{0,0,0,0}};
    const int row = kt * 16 + l16;      // kd row of ki^T
    #pragma unroll
    for (int ks = 0; ks < 4; ++ks) {
      short8 a = *(const short8*)&kiT_s[row * TC + (((ks * 4 + quad) ^ (row & 7)) << 3)];
      #pragma unroll
      for (int nn = 0; nn < 2; ++nn) {
        const int vd = (nb + nn) * 16 + l16;
        short8 b = *(const short8*)&vT_s[vd * TC + (((ks * 4 + quad) ^ (vd & 7)) << 3)];
        acc[nn] = __builtin_amdgcn_mfma_f32_16x16x32_bf16(a, b, acc[nn], 0, 0, 0);
      }
    }
    float wso[4];
    #pragma unroll
    for (int reg = 0; reg < 4; ++reg) wso[reg] = __shfl(wsoff_own, kt * 16 + quad * 4 + reg, 64);
    unsigned short* wkvg = wkv_u16 + ((size_t)bh * N + n) * (KD * KD);
    #pragma unroll
    for (int nn = 0; nn < 2; ++nn)
      #pragma unroll
      for (int reg = 0; reg < 4; ++reg)
        wkvg[(kt * 16 + quad * 4 + reg) * KD + (nb + nn) * 16 + l16] = f2bf(acc[nn][reg] * wso[reg]);
  }

  // ---- fused A^T tiles + out = A@v (one ib per wave, no block sync) ----
  {
    const int ib = wv;
    const int i0 = ib * 16;
    const int irow = i0 + l16;
    const int rsw = (irow & 7) ^ ((irow >> 3) & 7);
    short8 b0 = *(const short8*)&rd_s[irow * KD + ((quad ^ rsw) << 3)];
    short8 b1 = *(const short8*)&rd_s[irow * KD + (((4 + quad) ^ rsw) << 3)];
    const float diag_i = bf2f(diagg[irow]);
    f32x4 oacc[4] = {{0,0,0,0},{0,0,0,0},{0,0,0,0},{0,0,0,0}};
    const int npairs = (ib + 2) >> 1;
    unsigned short* astw = Ast + wv * 640;
    for (int jp = 0; jp < npairs; ++jp) {
      #pragma unroll
      for (int jj = 0; jj < 2; ++jj) {
        const int j = jp * 2 + jj;
        short4_t pk;
        if (j <= ib) {
          const int jrow = j * 16 + l16;
          const int jsw = (jrow & 7) ^ ((jrow >> 3) & 7);
          short8 a0 = *(const short8*)&ki_s[jrow * KD + ((quad ^ jsw) << 3)];
          short8 a1 = *(const short8*)&ki_s[jrow * KD + (((4 + quad) ^ jsw) << 3)];
          f32x4 at = {0, 0, 0, 0};
          at = __builtin_amdgcn_mfma_f32_16x16x32_bf16(a0, b0, at, 0, 0, 0);
          at = __builtin_amdgcn_mfma_f32_16x16x32_bf16(a1, b1, at, 0, 0, 0);
          #pragma unroll
          for (int reg = 0; reg < 4; ++reg) {
            const int je = j * 16 + quad * 4 + reg;
            float val = at[reg];
            if (j == ib) val = (je < irow) ? val : ((je == irow) ? diag_i : 0.f);
            pk[reg] = (short)f2bf(val);
          }
        } else {
          pk = (short4_t)0;  // guard half for even ib
        }
        *(short4_t*)&astw[l16 * 40 + jj * 16 + quad * 4] = pk;
      }
      short8 af = *(const short8*)&astw[l16 * 40 + quad * 8];
      #pragma unroll
      for (int nn = 0; nn < 4; ++nn) {
        const int vd = nn * 16 + l16;
        short8 bv = *(const short8*)&vT_s[vd * TC + (((jp * 4 + quad) ^ (vd & 7)) << 3)];
        oacc[nn] = __builtin_amdgcn_mfma_f32_16x16x32_bf16(af, bv, oacc[nn], 0, 0, 0);
      }
    }
    float* og = out + base;
    #pragma unroll
    for (int nn = 0; nn < 4; ++nn)
      #pragma unroll
      for (int reg = 0; reg < 4; ++reg)
        og[(i0 + quad * 4 + reg) * KD + nn * 16 + l16] = oacc[nn][reg];
  }
}

// ---------------------------------------------------------------------------
// K2 (fused scan+apply, fully parallel): block = (bh, n), BH*N = 1024 blocks.
// Each block recomputes S_n itself by scanning wkv[0..n-1] (L2/L3-hot: wkv
// is only 8.4 MB total). Then out += rw @ S_n with the accumulator repacked
// through a 17 KB LDS half-tile so the global RMW is float4 both ways.
// LDS 25,600 B -> 6 blocks/CU (24 waves/CU). (unchanged)
// ---------------------------------------------------------------------------
__global__ __launch_bounds__(256, 6)
void rwkv_scan_apply(const unsigned short* __restrict__ wkv_u16,
                     const float* __restrict__ wse_ws,
                     const float* __restrict__ st_in,
                     const unsigned short* __restrict__ rw_u16,
                     float* __restrict__ out, float* __restrict__ final_out, int N) {
  __shared__ alignas(16) unsigned short sT[KD * KD];    // 8 KB: S_n^T swizzled bf16
  __shared__ alignas(16) float obuf[64 * 68];           // 17,408 B: half-tile f32, stride 68

  const int bid = blockIdx.x;
  const int n = bid % N, bh = bid / N;
  const int tid = threadIdx.x;

  // ---- per-thread prefix scan: thread owns (kd = tid>>2, vd = v0..v0+15) ----
  const int kd = tid >> 2, v0 = (tid & 3) * 16;
  const size_t sbase = (size_t)bh * (KD * KD);
  float s[16];
  #pragma unroll
  for (int i = 0; i < 16; i += 4)
    *(f32x4*)&s[i] = *(const f32x4*)&st_in[sbase + kd * KD + v0 + i];

  const float* wseb = wse_ws + (size_t)bh * N * KD + kd;
  const unsigned short* wkvb = wkv_u16 + (size_t)bh * N * (KD * KD) + kd * KD + v0;

  {
    float e_c = 0.f; short8 x0_c = {0}, x1_c = {0};
    if (n > 0) {
      e_c = wseb[0];
      x0_c = *(const short8*)&wkvb[0];
      x1_c = *(const short8*)&wkvb[8];
    }
    for (int j = 0; j < n; ++j) {
      const float e = e_c; const short8 x0 = x0_c, x1 = x1_c;
      if (j + 1 < n) {
        e_c = wseb[(size_t)(j + 1) * KD];
        x0_c = *(const short8*)&wkvb[(size_t)(j + 1) * (KD * KD)];
        x1_c = *(const short8*)&wkvb[(size_t)(j + 1) * (KD * KD) + 8];
      }
      #pragma unroll
      for (int i = 0; i < 8; ++i) {
        s[i]     = s[i]     * e + bf2f((unsigned short)x0[i]);
        s[i + 8] = s[i + 8] * e + bf2f((unsigned short)x1[i]);
      }
    }
  }

  // ---- stage S_n^T into LDS (transpose + swizzle, from registers) ----
  {
    const int g = kd >> 3, k7 = kd & 7;
    #pragma unroll
    for (int i = 0; i < 16; ++i) {
      const int vd = v0 + i;
      sT[vd * KD + (((g ^ (vd & 7)) << 3) | k7)] = f2bf(s[i]);
    }
  }

  // ---- final state: only the n == N-1 blocks do one more step + write ----
  if (n == N - 1) {
    const float e = wseb[(size_t)(N - 1) * KD];
    const short8 x0 = *(const short8*)&wkvb[(size_t)(N - 1) * (KD * KD)];
    const short8 x1 = *(const short8*)&wkvb[(size_t)(N - 1) * (KD * KD) + 8];
    #pragma unroll
    for (int i = 0; i < 8; ++i) {
      s[i]     = s[i]     * e + bf2f((unsigned short)x0[i]);
      s[i + 8] = s[i + 8] * e + bf2f((unsigned short)x1[i]);
    }
    #pragma unroll
    for (int i = 0; i < 16; i += 4)
      *(f32x4*)&final_out[sbase + kd * KD + v0 + i] = *(const f32x4*)&s[i];
  }
  __syncthreads();

  // ---- out += rw @ S_n, epilogue via LDS half-tile for float4 RMW ----
  const int lane = tid & 63, wv = tid >> 6, quad = lane >> 4, l16 = lane & 15;
  const unsigned short* rwg = rw_u16 + ((size_t)bh * N + n) * (TC * KD);
  float* og = out + ((size_t)bh * N + n) * (TC * KD);
  #pragma unroll
  for (int half = 0; half < 2; ++half) {
    const int mt = wv + half * 4;
    const int trow = mt * 16 + l16;
    short8 a0 = *(const short8*)&rwg[trow * KD + quad * 8];
    short8 a1 = *(const short8*)&rwg[trow * KD + 32 + quad * 8];
    const int lr0 = (mt - half * 4) * 16 + quad * 4;   // local row base in obuf
    #pragma unroll
    for (int nn = 0; nn < 4; ++nn) {
      const int vd = nn * 16 + l16;
      short8 b0 = *(const short8*)&sT[vd * KD + ((quad ^ (vd & 7)) << 3)];
      short8 b1 = *(const short8*)&sT[vd * KD + (((4 + quad) ^ (vd & 7)) << 3)];
      f32x4 acc = {0, 0, 0, 0};
      acc = __builtin_amdgcn_mfma_f32_16x16x32_bf16(a0, b0, acc, 0, 0, 0);
      acc = __builtin_amdgcn_mfma_f32_16x16x32_bf16(a1, b1, acc, 0, 0, 0);
      #pragma unroll
      for (int reg = 0; reg < 4; ++reg)
        obuf[(lr0 + reg) * 68 + nn * 16 + l16] = acc[reg];
    }
    __syncthreads();
    // float4 RMW of 64 global rows (16 KB): 4 float4s per thread,
    // 1 KB contiguous per wave per instruction.
    {
      float* ogh = og + half * 64 * KD;
      #pragma unroll
      for (int i = 0; i < 4; ++i) {
        const int f = tid + i * 256;            // float4 index 0..1023
        const int row = f >> 4, c4 = (f & 15) * 4;
        f32x4 l = *(const f32x4*)&obuf[row * 68 + c4];
        f32x4 gv = *(const f32x4*)&ogh[row * KD + c4];
        gv += l;
        *(f32x4*)&ogh[row * KD + c4] = gv;
      }
    }
    __syncthreads();
  }
}

// ---------------------------------------------------------------------------
// Workspace (~24.75 MB): [wkv u16: BH*N*K*K][wse f32: BH*N*K]
//                        [rw u16: BH*T*K][diag u16: BH*N*TC]
// ---------------------------------------------------------------------------
extern "C" void kernel_launch(void* const* d_in, const int* in_sizes, int n_in,
                              void* d_out, int out_size, void* d_ws, size_t ws_size,
                              hipStream_t stream) {
  const float* r = (const float*)d_in[0];
  const float* k = (const float*)d_in[1];
  const float* v = (const float*)d_in[2];
  const float* w = (const float*)d_in[3];
  const float* u = (const float*)d_in[4];
  const float* st0 = (const float*)d_in[5];
  float* out = (float*)d_out;

  const int BH = in_sizes[5] / (KD * KD);  // 64
  const int H = in_sizes[4] / KD;          // 16
  const int T = in_sizes[0] / (BH * KD);   // 2048
  const int N = T / TC;                    // 16

  unsigned short* wkv_u16 = (unsigned short*)d_ws;
  float* wse_ws = (float*)(wkv_u16 + (size_t)BH * N * KD * KD);
  unsigned short* rw_u16 = (unsigned short*)(wse_ws + (size_t)BH * N * KD);
  unsigned short* diag_u16 = rw_u16 + (size_t)BH * T * KD;
  float* final_out = out + (size_t)in_sizes[0];

  rwkv_intra_mfma<<<BH * N, 512, 0, stream>>>(r, k, v, w, u, out, wkv_u16, wse_ws,
                                              rw_u16, diag_u16, H, N);
  rwkv_scan_apply<<<BH * N, 256, 0, stream>>>(wkv_u16, wse_ws, st0, rw_u16,
                                              out, final_out, N);
}